// Round 3
// baseline (239.594 us; speedup 1.0000x reference)
//
#include <hip/hip_runtime.h>
#include <hip/hip_bf16.h>
#include <cstdint>
#include <cstddef>

// ---------------------------------------------------------------------------
// GraphHeterogenousCrossAttention — reduced computation, f32 I/O
//
// Only the i=2 (graph, T=1) hetero iteration affects the output:
//   Q     = nf @ Wnq + bnq          (Wnq = W_node@Wq folded, K=128)
//   q     = softmax over each 32-col head
//   P     = q + v * s/max(s,1e-8),  s = dot(q_head, k_head)   [65536,256]
//   out   = P @ W_out + b_out       (in-place on d_out)
// k,v are per-head constants from the graph feature. Edge path is dead code.
//
// All global tensors are FLOAT32 (reference dtype). bf16 conversion happens
// only in LDS staging for MFMA. Workspace use < 256 KB (small tables only);
// P lives in d_out as f32, final GEMM is in-place (block owns its 128-row
// strip; all P reads complete before epilogue writes).
// ---------------------------------------------------------------------------

typedef __attribute__((ext_vector_type(8))) short short8;
typedef __attribute__((ext_vector_type(4))) float floatx4;

using bf16 = __hip_bfloat16;

static constexpr int Mrows = 65536;   // B*N
static constexpr int Lcols = 256;

static __device__ __forceinline__ short f2bs(float x) {
  bf16 h = __float2bfloat16(x);
  return *reinterpret_cast<short*>(&h);
}

// ---------------------------------------------------------------------------
// wnq_t[j*128 + r] = bf16( sum_l W_node[r,l] * Wq[l,j] )   (transposed store)
// grid 128 blocks (r), 256 threads (j).
__global__ void k_wnq(const float* __restrict__ Wn, const float* __restrict__ Wq,
                      short* __restrict__ wnq_t) {
  __shared__ float row[256];
  const int r = blockIdx.x, j = threadIdx.x;
  row[j] = Wn[r * 256 + j];
  __syncthreads();
  float acc = 0.f;
  for (int l = 0; l < 256; ++l) acc += row[l] * Wq[l * 256 + j];
  wnq_t[j * 128 + r] = f2bs(acc);
}

// ---------------------------------------------------------------------------
// wto_t[c*256 + r] = bf16( W_out[r,c] )
__global__ void k_transpose_out(const float* __restrict__ src,
                                short* __restrict__ dst) {
  int idx = blockIdx.x * 256 + threadIdx.x;   // 65536 total
  int r = idx >> 8, c = idx & 255;
  dst[c * 256 + r] = f2bs(src[idx]);
}

// ---------------------------------------------------------------------------
// Graph constants + fused bias:
//   lg   = energy @ W_graph + b_graph                        [256]
//   kvec = per-32-head softmax(lg @ Wk[2] + bk[2])
//   vvec = lg @ Wv[2] + bv[2]
//   bnq  = bq + b_node @ Wq
// One block, 256 threads.
__global__ void k_graph_setup(const float* __restrict__ energy,
                              const float* __restrict__ W_graph,
                              const float* __restrict__ b_graph,
                              const float* __restrict__ Wk,
                              const float* __restrict__ bk,
                              const float* __restrict__ Wv,
                              const float* __restrict__ bv,
                              const float* __restrict__ b_node,
                              const float* __restrict__ Wq,
                              const float* __restrict__ bq,
                              float* __restrict__ kvec,
                              float* __restrict__ vvec,
                              float* __restrict__ bnq) {
  __shared__ float ev[32];
  __shared__ float lg[256];
  __shared__ float kl[256];
  __shared__ float bn[256];
  const int j = threadIdx.x;
  if (j < 32) ev[j] = energy[j];
  bn[j] = b_node[j];
  __syncthreads();

  float acc = b_graph[j];
#pragma unroll
  for (int d = 0; d < 32; ++d) acc += ev[d] * W_graph[d * 256 + j];
  lg[j] = acc;
  __syncthreads();

  const float* Wk2 = Wk + 2 * 256 * 256;
  const float* Wv2 = Wv + 2 * 256 * 256;
  float ka = bk[2 * 256 + j];
  float va = bv[2 * 256 + j];
  float bb = bq[j];
  for (int d = 0; d < 256; ++d) {
    float l = lg[d];
    ka += l * Wk2[d * 256 + j];
    va += l * Wv2[d * 256 + j];
    bb += bn[d] * Wq[d * 256 + j];
  }
  kl[j] = ka;
  vvec[j] = va;
  bnq[j] = bb;
  __syncthreads();

  const int h0 = j & ~31;
  float mx = -1e30f;
  for (int t = 0; t < 32; ++t) mx = fmaxf(mx, kl[h0 + t]);
  float s = 0.f;
  for (int t = 0; t < 32; ++t) s += __expf(kl[h0 + t] - mx);
  kvec[j] = __expf(kl[j] - mx) / s;
}

// ---------------------------------------------------------------------------
// MFMA GEMM:  C[M,256] = A[M,K](f32) @ W + bias, W given transposed as
// bf16 Wt[256 cols][K].  A converted f32->bf16 during LDS staging.
// Block: 512 threads (8 waves), tile 128 rows x 256 cols, wave -> 64x64
// (4x4 frags of 16x16x32).  grid = (M/128).
// MODE 0: bias epilogue (f32 store).  MODE 1: per-head softmax + q + v*ratio.
// In-place safe when Cout==A: block reads only its own 128-row strip, all
// reads complete before epilogue writes.
template <int K, int MODE>
__global__ __launch_bounds__(512, 2)
void k_gemm(const float* __restrict__ Ag,
            const short* __restrict__ Wg,      // bf16 bits, [256][K]
            const float* __restrict__ bias,
            const float* __restrict__ kvec,
            const float* __restrict__ vvec,
            float* __restrict__ Cout) {
  __shared__ short As[128 * 64];   // A tile bf16: [128 rows][64 k]  (16 KB)
  __shared__ short Ws[256 * 64];   // W tile bf16: [256 cols][64 k]  (32 KB)

  const int t = threadIdx.x;
  const int lane = t & 63;
  const int l15 = lane & 15;
  const int lhi = lane >> 4;          // quad 0..3
  const int w = t >> 6;               // wave 0..7
  const int rw = (w >> 2) * 64;       // wave row base in tile
  const int cw = (w & 3) * 64;        // wave col base in tile

  const int rowBase = blockIdx.x * 128;

  floatx4 acc[4][4];
#pragma unroll
  for (int m = 0; m < 4; ++m)
#pragma unroll
    for (int n = 0; n < 4; ++n) acc[m][n] = (floatx4){0.f, 0.f, 0.f, 0.f};

  for (int k0 = 0; k0 < K; k0 += 64) {
    if (k0) __syncthreads();
    // --- A: 128x64 f32 -> bf16. 512 groups of 16 elems, one per thread.
    {
      const int row = t >> 2;
      const int cg = (t & 3) << 4;
      const float* src = Ag + (size_t)(rowBase + row) * K + k0 + cg;
      float4 f0 = *(const float4*)(src + 0);
      float4 f1 = *(const float4*)(src + 4);
      float4 f2 = *(const float4*)(src + 8);
      float4 f3 = *(const float4*)(src + 12);
      short tmp[16];
      tmp[0] = f2bs(f0.x); tmp[1] = f2bs(f0.y); tmp[2] = f2bs(f0.z); tmp[3] = f2bs(f0.w);
      tmp[4] = f2bs(f1.x); tmp[5] = f2bs(f1.y); tmp[6] = f2bs(f1.z); tmp[7] = f2bs(f1.w);
      tmp[8] = f2bs(f2.x); tmp[9] = f2bs(f2.y); tmp[10] = f2bs(f2.z); tmp[11] = f2bs(f2.w);
      tmp[12] = f2bs(f3.x); tmp[13] = f2bs(f3.y); tmp[14] = f2bs(f3.z); tmp[15] = f2bs(f3.w);
      *(short8*)(&As[row * 64 + cg]) = *(short8*)(&tmp[0]);
      *(short8*)(&As[row * 64 + cg + 8]) = *(short8*)(&tmp[8]);
    }
    // --- W: 256x64 bf16, 2048 short8, 4 per thread.
#pragma unroll
    for (int i = 0; i < 4; ++i) {
      int f = i * 512 + t;
      int row = f >> 3;
      int col = (f & 7) << 3;
      *(short8*)(&Ws[row * 64 + col]) =
          *(const short8*)(Wg + (size_t)row * K + k0 + col);
    }
    __syncthreads();

#pragma unroll
    for (int kk = 0; kk < 64; kk += 32) {
      short8 af[4], bfr[4];
#pragma unroll
      for (int m = 0; m < 4; ++m)
        af[m] = *(const short8*)(&As[(rw + m * 16 + l15) * 64 + kk + lhi * 8]);
#pragma unroll
      for (int n = 0; n < 4; ++n)
        bfr[n] = *(const short8*)(&Ws[(cw + n * 16 + l15) * 64 + kk + lhi * 8]);
#pragma unroll
      for (int m = 0; m < 4; ++m)
#pragma unroll
        for (int n = 0; n < 4; ++n)
          acc[m][n] = __builtin_amdgcn_mfma_f32_16x16x32_bf16(af[m], bfr[n],
                                                              acc[m][n], 0, 0, 0);
    }
  }

  // ---- epilogue ----  C/D layout: col = lane&15, row = (lane>>4)*4 + reg
  if constexpr (MODE == 0) {
#pragma unroll
    for (int n = 0; n < 4; ++n) {
      const int col = cw + n * 16 + l15;
      const float bb = bias[col];
#pragma unroll
      for (int m = 0; m < 4; ++m) {
        const int row0 = rowBase + rw + m * 16 + lhi * 4;
#pragma unroll
        for (int r = 0; r < 4; ++r)
          Cout[(size_t)(row0 + r) * Lcols + col] = acc[m][n][r] + bb;
      }
    }
  } else {
    // per-32-col-head softmax + linear-attention correction, f32 store
#pragma unroll
    for (int tt = 0; tt < 2; ++tt) {
      const int col0 = cw + tt * 32 + l15;
      const int col1 = col0 + 16;
      const float b0 = bias[col0], b1 = bias[col1];
      const float k0v = kvec[col0], k1v = kvec[col1];
      const float v0v = vvec[col0], v1v = vvec[col1];
#pragma unroll
      for (int m = 0; m < 4; ++m) {
        const int row0 = rowBase + rw + m * 16 + lhi * 4;
#pragma unroll
        for (int r = 0; r < 4; ++r) {
          float x0 = acc[m][2 * tt][r] + b0;
          float x1 = acc[m][2 * tt + 1][r] + b1;
          float mx = fmaxf(x0, x1);
          mx = fmaxf(mx, __shfl_xor(mx, 1));
          mx = fmaxf(mx, __shfl_xor(mx, 2));
          mx = fmaxf(mx, __shfl_xor(mx, 4));
          mx = fmaxf(mx, __shfl_xor(mx, 8));
          float e0 = __expf(x0 - mx), e1 = __expf(x1 - mx);
          float s = e0 + e1;
          s += __shfl_xor(s, 1);
          s += __shfl_xor(s, 2);
          s += __shfl_xor(s, 4);
          s += __shfl_xor(s, 8);
          float inv = 1.0f / s;
          float q0 = e0 * inv, q1 = e1 * inv;
          float d = q0 * k0v + q1 * k1v;
          d += __shfl_xor(d, 1);
          d += __shfl_xor(d, 2);
          d += __shfl_xor(d, 4);
          d += __shfl_xor(d, 8);
          float ratio = d / fmaxf(d, 1e-8f);
          Cout[(size_t)(row0 + r) * Lcols + col0] = q0 + v0v * ratio;
          Cout[(size_t)(row0 + r) * Lcols + col1] = q1 + v1v * ratio;
        }
      }
    }
  }
}

// ---------------------------------------------------------------------------
extern "C" void kernel_launch(void* const* d_in, const int* in_sizes, int n_in,
                              void* d_out, int out_size, void* d_ws, size_t ws_size,
                              hipStream_t stream) {
  const float* node_features = (const float*)d_in[0];
  // d_in[1] edge_features: dead code
  const float* energy  = (const float*)d_in[2];
  const float* W_node  = (const float*)d_in[3];
  const float* b_node  = (const float*)d_in[4];
  // d_in[5,6] W_edge/b_edge: dead code
  const float* W_graph = (const float*)d_in[7];
  const float* b_graph = (const float*)d_in[8];
  const float* Wq      = (const float*)d_in[9];
  const float* bq      = (const float*)d_in[10];
  const float* Wk      = (const float*)d_in[11];
  const float* bk      = (const float*)d_in[12];
  const float* Wv      = (const float*)d_in[13];
  const float* bv      = (const float*)d_in[14];
  const float* W_out   = (const float*)d_in[15];
  const float* b_out   = (const float*)d_in[16];

  // workspace layout — tables only, < 256 KB
  char* ws = (char*)d_ws;
  short* wnq_t = (short*)(ws);                  // 256*128*2 = 65536 B
  short* wto_t = (short*)(ws + 65536);          // 256*256*2 = 131072 B
  float* kvec  = (float*)(ws + 196608);         // 1 KB
  float* vvec  = (float*)(ws + 197632);         // 1 KB
  float* bnq   = (float*)(ws + 198656);         // 1 KB

  float* P = (float*)d_out;                     // P lives in d_out

  // 1) small setup kernels
  k_wnq<<<dim3(128), dim3(256), 0, stream>>>(W_node, Wq, wnq_t);
  k_transpose_out<<<dim3(256), dim3(256), 0, stream>>>(W_out, wto_t);
  k_graph_setup<<<dim3(1), dim3(256), 0, stream>>>(
      energy, W_graph, b_graph, Wk, bk, Wv, bv, b_node, Wq, bq,
      kvec, vvec, bnq);

  // 2) P = softmax-attn(nf @ Wnq + bnq)   -> d_out   (K=128, MODE 1)
  k_gemm<128, 1><<<dim3(Mrows / 128), dim3(512), 0, stream>>>(
      node_features, wnq_t, bnq, kvec, vvec, P);

  // 3) out = P @ W_out + b_out            -> d_out in-place (K=256, MODE 0)
  k_gemm<256, 0><<<dim3(Mrows / 128), dim3(512), 0, stream>>>(
      P, wto_t, b_out, nullptr, nullptr, (float*)d_out);
}

// Round 4
// 215.138 us; speedup vs baseline: 1.1137x; 1.1137x over previous
//
#include <hip/hip_runtime.h>
#include <hip/hip_bf16.h>
#include <cstdint>
#include <cstddef>

// ---------------------------------------------------------------------------
// GraphHeterogenousCrossAttention — fully fused main path, f32 I/O
//
// Only the i=2 (graph, T=1) hetero iteration affects the output:
//   Q   = nf @ Wnq + bnq          (Wnq = W_node@Wq folded, K=128)
//   q   = softmax over each 32-col head (per-head logits are O(1): exp safe
//         without max-subtraction)
//   P   = q + v * s/max(s,1e-8),  s = dot(q_head, k_head)
//   out = P @ W_out + b_out
//
// Fused kernel: one block computes a 64-row x 256-col tile; P stays in LDS
// (never hits global). Traffic: read nf 33.5 MB + write out 67 MB only.
// Setup (Wnq fold, W_out transpose, graph constants) parallelized across
// 256 blocks each — round-3's single-block serial-latency setup (~150 us)
// was the dominant cost.
// ---------------------------------------------------------------------------

typedef __attribute__((ext_vector_type(8))) short short8;
typedef __attribute__((ext_vector_type(4))) float floatx4;

using bf16 = __hip_bfloat16;

static constexpr int Mrows = 65536;   // B*N
static constexpr int Lcols = 256;

static __device__ __forceinline__ short f2bs(float x) {
  bf16 h = __float2bfloat16(x);
  return *reinterpret_cast<short*>(&h);
}

// ---------------------------------------------------------------------------
// wnq_t[j*128 + r] = bf16( sum_l W_node[r,l] * Wq[l,j] )   (transposed)
// grid 256 blocks (j), 128 threads (r).
__global__ void k_wnq(const float* __restrict__ Wn, const float* __restrict__ Wq,
                      short* __restrict__ wnq_t) {
  __shared__ float wqc[256];
  const int j = blockIdx.x, t = threadIdx.x;
  wqc[t] = Wq[t * 256 + j];
  wqc[t + 128] = Wq[(t + 128) * 256 + j];
  __syncthreads();
  const float* wr = Wn + t * 256;
  float acc = 0.f;
#pragma unroll 8
  for (int l = 0; l < 256; ++l) acc += wr[l] * wqc[l];
  wnq_t[j * 128 + t] = f2bs(acc);
}

// ---------------------------------------------------------------------------
// wto_t[c*256 + r] = bf16( W_out[r,c] ).  grid 256 blocks (r), 256 threads (c).
__global__ void k_transpose_out(const float* __restrict__ src,
                                short* __restrict__ dst) {
  const int r = blockIdx.x, c = threadIdx.x;
  dst[c * 256 + r] = f2bs(src[r * 256 + c]);
}

// ---------------------------------------------------------------------------
// Per-column graph constants via parallel reduction. grid 256 (block j),
// 256 threads (thread d):
//   lg[d]   = b_graph[d] + energy @ W_graph[:,d]       (recomputed per block)
//   klbuf[j]= bk2[j] + sum_d lg[d]*Wk2[d,j]
//   vvec[j] = bv2[j] + sum_d lg[d]*Wv2[d,j]
//   bnq[j]  = bq[j]  + sum_d b_node[d]*Wq[d,j]
__global__ void k_consts(const float* __restrict__ energy,
                         const float* __restrict__ W_graph,
                         const float* __restrict__ b_graph,
                         const float* __restrict__ Wk,
                         const float* __restrict__ bk,
                         const float* __restrict__ Wv,
                         const float* __restrict__ bv,
                         const float* __restrict__ b_node,
                         const float* __restrict__ Wq,
                         const float* __restrict__ bq,
                         float* __restrict__ klbuf,
                         float* __restrict__ vvec,
                         float* __restrict__ bnq) {
  __shared__ float ev[32];
  __shared__ float r0[256], r1[256], r2[256];
  const int j = blockIdx.x, d = threadIdx.x;
  if (d < 32) ev[d] = energy[d];
  __syncthreads();

  float lgd = b_graph[d];
#pragma unroll
  for (int e = 0; e < 32; ++e) lgd += ev[e] * W_graph[e * 256 + d];

  r0[d] = lgd * Wk[2 * 65536 + d * 256 + j];
  r1[d] = lgd * Wv[2 * 65536 + d * 256 + j];
  r2[d] = b_node[d] * Wq[d * 256 + j];
  __syncthreads();
  for (int s = 128; s > 0; s >>= 1) {
    if (d < s) { r0[d] += r0[d + s]; r1[d] += r1[d + s]; r2[d] += r2[d + s]; }
    __syncthreads();
  }
  if (d == 0) {
    klbuf[j] = r0[0] + bk[512 + j];
    vvec[j]  = r1[0] + bv[512 + j];
    bnq[j]   = r2[0] + bq[j];
  }
}

// ---------------------------------------------------------------------------
// kvec = per-32-head softmax(klbuf).  1 block, 256 threads, LDS only.
__global__ void k_softmax_k(const float* __restrict__ klbuf,
                            float* __restrict__ kvec) {
  __shared__ float kl[256];
  const int j = threadIdx.x;
  kl[j] = klbuf[j];
  __syncthreads();
  const int h0 = j & ~31;
  float mx = -1e30f;
  for (int t = 0; t < 32; ++t) mx = fmaxf(mx, kl[h0 + t]);
  float s = 0.f;
  for (int t = 0; t < 32; ++t) s += __expf(kl[h0 + t] - mx);
  kvec[j] = __expf(kl[j] - mx) / s;
}

// ---------------------------------------------------------------------------
// Fused: Q-GEMM (K=128) -> per-head softmax + linear-attn -> out-GEMM (K=256)
// Block: 256 threads (4 waves), tile 64 rows x 256 cols; wave w owns cols
// [64w,64w+64) (4x4 frags of 16x16x32).  P lives in LDS (bf16).  grid=M/64.
// LDS strides padded +8 shorts -> 2-way bank aliasing (free, m136).
__global__ __launch_bounds__(256, 3)
void k_fused(const float* __restrict__ nf,
             const short* __restrict__ wnq,    // [256 j][128 k] bf16 bits
             const short* __restrict__ wto,    // [256 j][256 k] bf16 bits
             const float* __restrict__ bnq,
             const float* __restrict__ kvec,
             const float* __restrict__ vvec,
             const float* __restrict__ b_out,
             float* __restrict__ out) {
  constexpr int AS_STR = 136;            // 128 + 8 pad
  constexpr int WB_STR = 40;             // 32 + 8 pad (80 B rows, 16B-aligned)
  constexpr int PS_STR = 264;            // 256 + 8 pad
  constexpr int WOFF1  = 64 * AS_STR;    // 8704  (phase-1 W chunk)
  constexpr int WOFF2  = 64 * PS_STR;    // 16896 (phase-2 W chunk)
  __shared__ short smem[WOFF2 + 256 * WB_STR];   // 27136 shorts = 53 KB

  const int t = threadIdx.x;
  const int lane = t & 63;
  const int l15 = lane & 15;
  const int lhi = lane >> 4;             // quad 0..3
  const int cw = (t >> 6) * 64;          // wave col base
  const int rowBase = blockIdx.x * 64;

  // ---- stage A (nf rows, f32 -> bf16), once: As[64][AS_STR] ----
  {
    const int row = t >> 2;
    const int c0 = (t & 3) << 5;         // 0,32,64,96
    const float* src = nf + (size_t)(rowBase + row) * 128 + c0;
    short tmp[32];
#pragma unroll
    for (int i = 0; i < 8; ++i) {
      float4 f = *(const float4*)(src + i * 4);
      tmp[i * 4 + 0] = f2bs(f.x); tmp[i * 4 + 1] = f2bs(f.y);
      tmp[i * 4 + 2] = f2bs(f.z); tmp[i * 4 + 3] = f2bs(f.w);
    }
#pragma unroll
    for (int i = 0; i < 4; ++i)
      *(short8*)(&smem[row * AS_STR + c0 + i * 8]) = *(short8*)(&tmp[i * 8]);
  }

  floatx4 acc[4][4];
#pragma unroll
  for (int m = 0; m < 4; ++m)
#pragma unroll
    for (int n = 0; n < 4; ++n) acc[m][n] = (floatx4){0.f, 0.f, 0.f, 0.f};

  // ---- phase 1: Q = nf @ Wnq, K=128 in 4 chunks of 32 ----
  for (int kc = 0; kc < 4; ++kc) {
    {
      const short* src = wnq + t * 128 + kc * 32;   // thread t -> col t
      short8 w0 = *(const short8*)(src);
      short8 w1 = *(const short8*)(src + 8);
      short8 w2 = *(const short8*)(src + 16);
      short8 w3 = *(const short8*)(src + 24);
      short* dst = &smem[WOFF1 + t * WB_STR];
      *(short8*)(dst) = w0;      *(short8*)(dst + 8) = w1;
      *(short8*)(dst + 16) = w2; *(short8*)(dst + 24) = w3;
    }
    __syncthreads();
    short8 af[4], bfv[4];
#pragma unroll
    for (int m = 0; m < 4; ++m)
      af[m] = *(const short8*)(&smem[(m * 16 + l15) * AS_STR + kc * 32 + lhi * 8]);
#pragma unroll
    for (int n = 0; n < 4; ++n)
      bfv[n] = *(const short8*)(&smem[WOFF1 + (cw + n * 16 + l15) * WB_STR + lhi * 8]);
#pragma unroll
    for (int m = 0; m < 4; ++m)
#pragma unroll
      for (int n = 0; n < 4; ++n)
        acc[m][n] = __builtin_amdgcn_mfma_f32_16x16x32_bf16(af[m], bfv[n],
                                                            acc[m][n], 0, 0, 0);
    __syncthreads();
  }

  // ---- epilogue 1: per-head softmax + q + v*ratio -> Ps (bf16 in LDS) ----
  // C/D layout: col = lane&15, row = (lane>>4)*4 + reg.
  // No max-subtraction: per-head logits are O(1) (std~1), exp is f32-safe.
#pragma unroll
  for (int tt = 0; tt < 2; ++tt) {
    const int col0 = cw + tt * 32 + l15;
    const int col1 = col0 + 16;
    const float b0 = bnq[col0], b1 = bnq[col1];
    const float k0v = kvec[col0], k1v = kvec[col1];
    const float v0v = vvec[col0], v1v = vvec[col1];
#pragma unroll
    for (int m = 0; m < 4; ++m) {
      const int row0 = m * 16 + lhi * 4;
#pragma unroll
      for (int r = 0; r < 4; ++r) {
        float e0 = __expf(acc[m][2 * tt][r] + b0);
        float e1 = __expf(acc[m][2 * tt + 1][r] + b1);
        float s = e0 + e1;
        float du = e0 * k0v + e1 * k1v;
#pragma unroll
        for (int msk = 1; msk <= 8; msk <<= 1) {
          s += __shfl_xor(s, msk);
          du += __shfl_xor(du, msk);
        }
        float inv = 1.0f / s;
        float d = du * inv;
        float ratio = d / fmaxf(d, 1e-8f);
        smem[(row0 + r) * PS_STR + col0] = f2bs(e0 * inv + v0v * ratio);
        smem[(row0 + r) * PS_STR + col1] = f2bs(e1 * inv + v1v * ratio);
      }
    }
  }
#pragma unroll
  for (int m = 0; m < 4; ++m)
#pragma unroll
    for (int n = 0; n < 4; ++n) acc[m][n] = (floatx4){0.f, 0.f, 0.f, 0.f};
  __syncthreads();

  // ---- phase 2: out = P @ W_out, K=256 in 8 chunks of 32 ----
  for (int kc = 0; kc < 8; ++kc) {
    {
      const short* src = wto + t * 256 + kc * 32;   // thread t -> col t
      short8 w0 = *(const short8*)(src);
      short8 w1 = *(const short8*)(src + 8);
      short8 w2 = *(const short8*)(src + 16);
      short8 w3 = *(const short8*)(src + 24);
      short* dst = &smem[WOFF2 + t * WB_STR];
      *(short8*)(dst) = w0;      *(short8*)(dst + 8) = w1;
      *(short8*)(dst + 16) = w2; *(short8*)(dst + 24) = w3;
    }
    __syncthreads();
    short8 af[4], bfv[4];
#pragma unroll
    for (int m = 0; m < 4; ++m)
      af[m] = *(const short8*)(&smem[(m * 16 + l15) * PS_STR + kc * 32 + lhi * 8]);
#pragma unroll
    for (int n = 0; n < 4; ++n)
      bfv[n] = *(const short8*)(&smem[WOFF2 + (cw + n * 16 + l15) * WB_STR + lhi * 8]);
#pragma unroll
    for (int m = 0; m < 4; ++m)
#pragma unroll
      for (int n = 0; n < 4; ++n)
        acc[m][n] = __builtin_amdgcn_mfma_f32_16x16x32_bf16(af[m], bfv[n],
                                                            acc[m][n], 0, 0, 0);
    __syncthreads();
  }

  // ---- epilogue 2: + b_out, f32 store ----
#pragma unroll
  for (int n = 0; n < 4; ++n) {
    const int col = cw + n * 16 + l15;
    const float bb = b_out[col];
#pragma unroll
    for (int m = 0; m < 4; ++m) {
      const int row0 = rowBase + m * 16 + lhi * 4;
#pragma unroll
      for (int r = 0; r < 4; ++r)
        out[(size_t)(row0 + r) * Lcols + col] = acc[m][n][r] + bb;
    }
  }
}

// ---------------------------------------------------------------------------
extern "C" void kernel_launch(void* const* d_in, const int* in_sizes, int n_in,
                              void* d_out, int out_size, void* d_ws, size_t ws_size,
                              hipStream_t stream) {
  const float* node_features = (const float*)d_in[0];
  // d_in[1] edge_features: dead code
  const float* energy  = (const float*)d_in[2];
  const float* W_node  = (const float*)d_in[3];
  const float* b_node  = (const float*)d_in[4];
  // d_in[5,6] W_edge/b_edge: dead code
  const float* W_graph = (const float*)d_in[7];
  const float* b_graph = (const float*)d_in[8];
  const float* Wq      = (const float*)d_in[9];
  const float* bq      = (const float*)d_in[10];
  const float* Wk      = (const float*)d_in[11];
  const float* bk      = (const float*)d_in[12];
  const float* Wv      = (const float*)d_in[13];
  const float* bv      = (const float*)d_in[14];
  const float* W_out   = (const float*)d_in[15];
  const float* b_out   = (const float*)d_in[16];

  // workspace: tables only (< 256 KB)
  char* ws = (char*)d_ws;
  short* wnq_t = (short*)(ws);                  // 256*128*2 = 65536 B
  short* wto_t = (short*)(ws + 65536);          // 256*256*2 = 131072 B
  float* klbuf = (float*)(ws + 196608);         // 1 KB
  float* kvec  = (float*)(ws + 197632);         // 1 KB
  float* vvec  = (float*)(ws + 198656);         // 1 KB
  float* bnq   = (float*)(ws + 199680);         // 1 KB

  k_wnq<<<dim3(256), dim3(128), 0, stream>>>(W_node, Wq, wnq_t);
  k_transpose_out<<<dim3(256), dim3(256), 0, stream>>>(W_out, wto_t);
  k_consts<<<dim3(256), dim3(256), 0, stream>>>(
      energy, W_graph, b_graph, Wk, bk, Wv, bv, b_node, Wq, bq,
      klbuf, vvec, bnq);
  k_softmax_k<<<dim3(1), dim3(256), 0, stream>>>(klbuf, kvec);

  k_fused<<<dim3(Mrows / 64), dim3(256), 0, stream>>>(
      node_features, wnq_t, wto_t, bnq, kvec, vvec, b_out, (float*)d_out);
}

// Round 5
// 196.795 us; speedup vs baseline: 1.2175x; 1.0932x over previous
//
#include <hip/hip_runtime.h>
#include <hip/hip_bf16.h>
#include <cstdint>
#include <cstddef>

// ---------------------------------------------------------------------------
// GraphHeterogenousCrossAttention — fused main path, f32 I/O, round 5
//
// Math (only the i=2 / graph / T=1 hetero branch matters):
//   Q   = nf @ Wnq + bnq          (Wnq = W_node@Wq folded, K=128)
//   q   = per-32-col-head softmax(Q)
//   P   = q + v * s/max(s,1e-8),  s = dot(q_head, k_head)
//   out = P @ W_out + b_out
//
// Round-5 structure change: W matrices are tiny and L2-resident, so B-frags
// are loaded DIRECTLY global->VGPR (no LDS staging, no K-loop barriers).
// Only 3 __syncthreads per block (round 4 had 13 -> barrier-drain bound,
// MfmaUtil 7%, nothing saturated). LDS = A/P union ~36 KB -> 4 blocks/CU.
// Setup merged into ONE 768-block kernel; k-softmax folded into k_fused.
// ---------------------------------------------------------------------------

typedef __attribute__((ext_vector_type(8))) short short8;
typedef __attribute__((ext_vector_type(4))) float floatx4;

using bf16 = __hip_bfloat16;

static constexpr int Mrows = 65536;   // B*N
static constexpr int Lcols = 256;

static __device__ __forceinline__ short f2bs(float x) {
  bf16 h = __float2bfloat16(x);
  return *reinterpret_cast<short*>(&h);
}

// ---------------------------------------------------------------------------
// Merged setup, grid = 768 blocks x 256 threads:
//  blocks [0,256):   wnq_t[j*128 + r] = bf16(sum_l W_node[r,l] Wq[l,j]), j=b
//  blocks [256,512): wto_t[c*256 + r] = bf16(W_out[r,c]),               r=b-256
//  blocks [512,768): klbuf/vvec/bnq column j = b-512 via LDS reduction
__global__ void k_setup(const float* __restrict__ W_node,
                        const float* __restrict__ Wq,
                        const float* __restrict__ W_out,
                        const float* __restrict__ energy,
                        const float* __restrict__ W_graph,
                        const float* __restrict__ b_graph,
                        const float* __restrict__ Wk,
                        const float* __restrict__ bk,
                        const float* __restrict__ Wv,
                        const float* __restrict__ bv,
                        const float* __restrict__ b_node,
                        const float* __restrict__ bq,
                        short* __restrict__ wnq_t,
                        short* __restrict__ wto_t,
                        float* __restrict__ klbuf,
                        float* __restrict__ vvec,
                        float* __restrict__ bnq) {
  const int b = blockIdx.x;
  const int t = threadIdx.x;

  if (b < 256) {
    // ---- Wnq fold (transposed store) ----
    __shared__ float wqc[256];
    const int j = b;
    wqc[t] = Wq[t * 256 + j];
    __syncthreads();
    if (t < 128) {
      const float* wr = W_node + t * 256;
      float acc = 0.f;
#pragma unroll 8
      for (int l = 0; l < 256; ++l) acc += wr[l] * wqc[l];
      wnq_t[j * 128 + t] = f2bs(acc);
    }
  } else if (b < 512) {
    // ---- W_out transpose ----
    const int r = b - 256;
    wto_t[t * 256 + r] = f2bs(W_out[r * 256 + t]);
  } else {
    // ---- graph constants, column j ----
    __shared__ float ev[32];
    __shared__ float r0[256], r1[256], r2[256];
    const int j = b - 512, d = t;
    if (d < 32) ev[d] = energy[d];
    __syncthreads();

    float lgd = b_graph[d];
#pragma unroll
    for (int e = 0; e < 32; ++e) lgd += ev[e] * W_graph[e * 256 + d];

    r0[d] = lgd * Wk[2 * 65536 + d * 256 + j];
    r1[d] = lgd * Wv[2 * 65536 + d * 256 + j];
    r2[d] = b_node[d] * Wq[d * 256 + j];
    __syncthreads();
    for (int s = 128; s > 0; s >>= 1) {
      if (d < s) { r0[d] += r0[d + s]; r1[d] += r1[d + s]; r2[d] += r2[d + s]; }
      __syncthreads();
    }
    if (d == 0) {
      klbuf[j] = r0[0] + bk[512 + j];
      vvec[j]  = r1[0] + bv[512 + j];
      bnq[j]   = r2[0] + bq[j];
    }
  }
}

// ---------------------------------------------------------------------------
// Fused: Q-GEMM (K=128) -> per-head softmax + linear-attn -> out-GEMM (K=256)
// Block: 256 threads (4 waves), tile 64 rows x 256 cols; wave w owns cols
// [64w,64w+64) as 4x4 frags of 16x16x32.  A and P live in LDS (union buffer);
// W/B-fragments load directly global->VGPR (L2-resident), so the K-loops have
// NO barriers.  3 __syncthreads total.  grid = M/64.
__global__ __launch_bounds__(256, 4)
void k_fused(const float* __restrict__ nf,
             const short* __restrict__ wnq,    // [256 j][128 k] bf16 bits
             const short* __restrict__ wto,    // [256 j][256 k] bf16 bits
             const float* __restrict__ klbuf,
             const float* __restrict__ bnq,
             const float* __restrict__ vvec,
             const float* __restrict__ b_out,
             float* __restrict__ out) {
  constexpr int AS_STR = 136;            // A row stride (shorts), 272 B
  constexpr int PS_STR = 264;            // P row stride (shorts), 528 B
  __shared__ short smem[64 * PS_STR];    // 33792 B (A uses first 17408 B)
  __shared__ float kl[256];
  __shared__ float kv[256];

  const int t = threadIdx.x;
  const int lane = t & 63;
  const int l15 = lane & 15;
  const int lhi = lane >> 4;             // quad 0..3
  const int cw = (t >> 6) * 64;          // wave col base
  const int rowBase = blockIdx.x * 64;

  kl[t] = klbuf[t];

  // ---- stage A (64 rows x 128 k, f32 -> bf16), once ----
  {
    const int row = t >> 2;
    const int c0 = (t & 3) << 5;         // 0,32,64,96
    const float* src = nf + (size_t)(rowBase + row) * 128 + c0;
    short tmp[32];
#pragma unroll
    for (int i = 0; i < 8; ++i) {
      float4 f = *(const float4*)(src + i * 4);
      tmp[i * 4 + 0] = f2bs(f.x); tmp[i * 4 + 1] = f2bs(f.y);
      tmp[i * 4 + 2] = f2bs(f.z); tmp[i * 4 + 3] = f2bs(f.w);
    }
#pragma unroll
    for (int i = 0; i < 4; ++i)
      *(short8*)(&smem[row * AS_STR + c0 + i * 8]) = *(short8*)(&tmp[i * 8]);
  }
  __syncthreads();                       // (1) A + kl visible

  // per-thread k-softmax (reads/writes stay within this thread's wave)
  {
    const int h0 = t & ~31;
    float mx = -1e30f;
#pragma unroll 8
    for (int i = 0; i < 32; ++i) mx = fmaxf(mx, kl[h0 + i]);
    float s = 0.f;
#pragma unroll 8
    for (int i = 0; i < 32; ++i) s += __expf(kl[h0 + i] - mx);
    kv[t] = __expf(kl[t] - mx) / s;
  }

  floatx4 acc[4][4];
#pragma unroll
  for (int m = 0; m < 4; ++m)
#pragma unroll
    for (int n = 0; n < 4; ++n) acc[m][n] = (floatx4){0.f, 0.f, 0.f, 0.f};

  // ---- phase 1: Q = A @ Wnq, K=128, B-frags direct from global (L2) ----
  {
    const short* wb = wnq + (cw + l15) * 128 + lhi * 8;
#pragma unroll
    for (int kc = 0; kc < 4; ++kc) {
      short8 af[4], bfv[4];
#pragma unroll
      for (int n = 0; n < 4; ++n)
        bfv[n] = *(const short8*)(wb + n * 16 * 128 + kc * 32);
#pragma unroll
      for (int m = 0; m < 4; ++m)
        af[m] = *(const short8*)(&smem[(m * 16 + l15) * AS_STR + kc * 32 + lhi * 8]);
#pragma unroll
      for (int m = 0; m < 4; ++m)
#pragma unroll
        for (int n = 0; n < 4; ++n)
          acc[m][n] = __builtin_amdgcn_mfma_f32_16x16x32_bf16(af[m], bfv[n],
                                                              acc[m][n], 0, 0, 0);
    }
  }
  __syncthreads();                       // (2) A reads done; P may overwrite

  // ---- epilogue 1: softmax + q + v*ratio -> P (bf16, LDS) ----
  // C/D layout: col = lane&15, row = (lane>>4)*4 + reg.  Logits are O(1):
  // exp without max-subtraction is f32-safe (validated r3/r4, absmax .0156).
#pragma unroll
  for (int tt = 0; tt < 2; ++tt) {
    const int col0 = cw + tt * 32 + l15;
    const int col1 = col0 + 16;
    const float b0 = bnq[col0], b1 = bnq[col1];
    const float k0v = kv[col0], k1v = kv[col1];
    const float v0v = vvec[col0], v1v = vvec[col1];
#pragma unroll
    for (int m = 0; m < 4; ++m) {
      const int row0 = m * 16 + lhi * 4;
#pragma unroll
      for (int r = 0; r < 4; ++r) {
        float e0 = __expf(acc[m][2 * tt][r] + b0);
        float e1 = __expf(acc[m][2 * tt + 1][r] + b1);
        float s = e0 + e1;
        float du = e0 * k0v + e1 * k1v;
#pragma unroll
        for (int msk = 1; msk <= 8; msk <<= 1) {
          s += __shfl_xor(s, msk);
          du += __shfl_xor(du, msk);
        }
        float inv = 1.0f / s;
        float d = du * inv;
        float ratio = d / fmaxf(d, 1e-8f);
        smem[(row0 + r) * PS_STR + col0] = f2bs(e0 * inv + v0v * ratio);
        smem[(row0 + r) * PS_STR + col1] = f2bs(e1 * inv + v1v * ratio);
      }
    }
  }
#pragma unroll
  for (int m = 0; m < 4; ++m)
#pragma unroll
    for (int n = 0; n < 4; ++n) acc[m][n] = (floatx4){0.f, 0.f, 0.f, 0.f};
  __syncthreads();                       // (3) P visible to all waves

  // ---- phase 2: out = P @ W_out, K=256, B-frags direct from global ----
  {
    const short* wb = wto + (cw + l15) * 256 + lhi * 8;
#pragma unroll
    for (int kc = 0; kc < 8; ++kc) {
      short8 af[4], bfv[4];
#pragma unroll
      for (int n = 0; n < 4; ++n)
        bfv[n] = *(const short8*)(wb + n * 16 * 256 + kc * 32);
#pragma unroll
      for (int m = 0; m < 4; ++m)
        af[m] = *(const short8*)(&smem[(m * 16 + l15) * PS_STR + kc * 32 + lhi * 8]);
#pragma unroll
      for (int m = 0; m < 4; ++m)
#pragma unroll
        for (int n = 0; n < 4; ++n)
          acc[m][n] = __builtin_amdgcn_mfma_f32_16x16x32_bf16(af[m], bfv[n],
                                                              acc[m][n], 0, 0, 0);
    }
  }

  // ---- epilogue 2: + b_out, f32 store ----
#pragma unroll
  for (int n = 0; n < 4; ++n) {
    const int col = cw + n * 16 + l15;
    const float bb = b_out[col];
#pragma unroll
    for (int m = 0; m < 4; ++m) {
      const int row0 = rowBase + m * 16 + lhi * 4;
#pragma unroll
      for (int r = 0; r < 4; ++r)
        out[(size_t)(row0 + r) * Lcols + col] = acc[m][n][r] + bb;
    }
  }
}

// ---------------------------------------------------------------------------
extern "C" void kernel_launch(void* const* d_in, const int* in_sizes, int n_in,
                              void* d_out, int out_size, void* d_ws, size_t ws_size,
                              hipStream_t stream) {
  const float* node_features = (const float*)d_in[0];
  // d_in[1] edge_features: dead code
  const float* energy  = (const float*)d_in[2];
  const float* W_node  = (const float*)d_in[3];
  const float* b_node  = (const float*)d_in[4];
  // d_in[5,6] W_edge/b_edge: dead code
  const float* W_graph = (const float*)d_in[7];
  const float* b_graph = (const float*)d_in[8];
  const float* Wq      = (const float*)d_in[9];
  const float* bq      = (const float*)d_in[10];
  const float* Wk      = (const float*)d_in[11];
  const float* bk      = (const float*)d_in[12];
  const float* Wv      = (const float*)d_in[13];
  const float* bv      = (const float*)d_in[14];
  const float* W_out   = (const float*)d_in[15];
  const float* b_out   = (const float*)d_in[16];

  // workspace: tables only (< 256 KB)
  char* ws = (char*)d_ws;
  short* wnq_t = (short*)(ws);                  // 256*128*2 = 65536 B
  short* wto_t = (short*)(ws + 65536);          // 256*256*2 = 131072 B
  float* klbuf = (float*)(ws + 196608);         // 1 KB
  float* vvec  = (float*)(ws + 197632);         // 1 KB
  float* bnq   = (float*)(ws + 198656);         // 1 KB

  k_setup<<<dim3(768), dim3(256), 0, stream>>>(
      W_node, Wq, W_out, energy, W_graph, b_graph, Wk, bk, Wv, bv,
      b_node, bq, wnq_t, wto_t, klbuf, vvec, bnq);

  k_fused<<<dim3(Mrows / 64), dim3(256), 0, stream>>>(
      node_features, wnq_t, wto_t, klbuf, bnq, vvec, b_out, (float*)d_out);
}